// Round 11
// baseline (351.215 us; speedup 1.0000x reference)
//
#include <hip/hip_runtime.h>
#include <math.h>

// Problem constants
#define NN       16384
#define IN_DIM   64
#define CC       4
#define NMAT     (NN * CC)

// Taylor coefficients 1/k!
#define C0 1.0f
#define C1 1.0f
#define C2 0.5f
#define C3 0.16666666666666666f
#define C4 0.041666666666666664f
#define C5 0.008333333333333333f
#define C6 0.001388888888888889f
#define C7 1.984126984126984e-4f
#define C8 2.48015873015873e-5f

typedef __attribute__((ext_vector_type(8))) short bf16x8;   // 8 bf16 = 4 VGPR
typedef __attribute__((ext_vector_type(4))) float f32x4;    // C/D frag

#define MFMA16(A, B, C) __builtin_amdgcn_mfma_f32_16x16x32_bf16((A), (B), (C), 0, 0, 0)
#define SHF(x, src) ((unsigned)__shfl((int)(x), (src)))

__device__ __forceinline__ float hif(float x) {
    return __builtin_bit_cast(float, __builtin_bit_cast(unsigned, x) & 0xFFFF0000u);
}
__device__ __forceinline__ unsigned pk2(float a, float b) {   // bf16(a) | bf16(b)<<16
    return (__builtin_bit_cast(unsigned, a) >> 16) |
           (__builtin_bit_cast(unsigned, b) & 0xFFFF0000u);
}

// ---------------------------------------------------------------------------
// Phase 1: B[n,c,i,j] = sum_k dX[n,k] * (Ar + i*Ai)[k,c,i,j]  -> ws (interleaved)
// ---------------------------------------------------------------------------
__global__ __launch_bounds__(256)
void ax_kernel(const float* __restrict__ dX, const float* __restrict__ Ar,
               const float* __restrict__ Ai, float* __restrict__ ws)
{
    const int t  = threadIdx.x;
    const int nb = blockIdx.x * 8;
    const int c  = t >> 6;
    const int i  = (t >> 2) & 15;
    const int j0 = (t & 3) * 4;

    float accre[8][4], accim[8][4];
#pragma unroll
    for (int nn_ = 0; nn_ < 8; ++nn_)
#pragma unroll
        for (int jj = 0; jj < 4; ++jj) { accre[nn_][jj] = 0.f; accim[nn_][jj] = 0.f; }

#pragma unroll 2
    for (int k = 0; k < IN_DIM; ++k) {
        const int base = (k * CC + c) * 256 + i * 16 + j0;
        const float4 ar = *reinterpret_cast<const float4*>(Ar + base);
        const float4 ai = *reinterpret_cast<const float4*>(Ai + base);
#pragma unroll
        for (int nn_ = 0; nn_ < 8; ++nn_) {
            const float dxv = dX[(nb + nn_) * IN_DIM + k];
#pragma unroll
            for (int jj = 0; jj < 4; ++jj) {
                accre[nn_][jj] = fmaf(dxv, (&ar.x)[jj], accre[nn_][jj]);
                accim[nn_][jj] = fmaf(dxv, (&ai.x)[jj], accim[nn_][jj]);
            }
        }
    }
#pragma unroll
    for (int nn_ = 0; nn_ < 8; ++nn_) {
        const int m = (nb + nn_) * CC + c;
        float* o = ws + (size_t)m * 512 + (i * 16 + j0) * 2;
        reinterpret_cast<float4*>(o)[0] =
            make_float4(accre[nn_][0], accim[nn_][0], accre[nn_][1], accim[nn_][1]);
        reinterpret_cast<float4*>(o)[1] =
            make_float4(accre[nn_][2], accim[nn_][2], accre[nn_][3], accim[nn_][3]);
    }
}

// ---------------------------------------------------------------------------
// Phase 2 (MFMA, register-resident, ZERO LDS): one matrix per wave.
// State in C/D layout (lane c=l&15, g=l>>4 holds M[4g+q][c]).
// Frags built by ds_bpermute from packed bf16 hi/lo state:
//   B-style set(M): 16 shuffles -> plane frags PX/PY (hi+lo), j-ordered.
//   Feeding sel4(set) as B-operand presents M; as A-operand presents M^T.
// Pair-track for squarings: (T, U=T^T): T'=T*T uses A=plain(set(U)),
// B=B12(set(T)); U'=U*U uses A=plain(set(T)), B=B12(set(U)).
// U seeded as conj(S), S = poly(-A) run alongside the T-Horner.
// A1^T = -conj(A1), Z^T = conj(Z) -> their A-presentations are sign tweaks.
// ---------------------------------------------------------------------------
__global__ __launch_bounds__(256)
void expm_mfma_kernel(const float* __restrict__ dX, const float* __restrict__ Ar,
                      const float* __restrict__ Ai, const float* __restrict__ ws,
                      float* __restrict__ out, const int use_ws, const int real_only)
{
    const int t = threadIdx.x;
    const int w = t >> 6;
    const int l = t & 63;

    const int m  = blockIdx.x * 4 + w;
    const int n  = m >> 2;
    const int cc = m & 3;

    const int c  = l & 15;
    const int g  = l >> 4;
    const int gh = g & 1;
    const bool gs = (g >= 2);          // k>=16 half (Y-plane side of frags)
    const int s0 = 32 * gh + c;        // bperm src lane for j=0..3
    const int s1 = s0 + 16;            // bperm src lane for j=4..7
    const unsigned SG = 0x80008000u;

    float dq[4];
#pragma unroll
    for (int q = 0; q < 4; ++q) dq[q] = ((4 * g + q) == c) ? 1.f : 0.f;

    // ---- load AX (C/D ownership) + transposed elements; skew-project
    float aRe[4], aIm[4];
    if (use_ws) {
        const float* gp = ws + (size_t)m * 512;
#pragma unroll
        for (int q = 0; q < 4; ++q) {
            const int r = 4 * g + q;
            const float2 v = *reinterpret_cast<const float2*>(gp + (r * 16 + c) * 2);
            const float2 u = *reinterpret_cast<const float2*>(gp + (c * 16 + r) * 2);
            aRe[q] = 0.5f * (v.x - u.x);
            aIm[q] = 0.5f * (v.y + u.y);
        }
    } else {
        float bRe[4] = {0,0,0,0}, bIm[4] = {0,0,0,0}, uRe[4] = {0,0,0,0}, uIm[4] = {0,0,0,0};
        for (int k = 0; k < IN_DIM; ++k) {
            const float dxv = dX[n * IN_DIM + k];
            const int base = (k * CC + cc) * 256;
#pragma unroll
            for (int q = 0; q < 4; ++q) {
                const int r = 4 * g + q;
                bRe[q] = fmaf(dxv, Ar[base + r * 16 + c], bRe[q]);
                bIm[q] = fmaf(dxv, Ai[base + r * 16 + c], bIm[q]);
                uRe[q] = fmaf(dxv, Ar[base + c * 16 + r], uRe[q]);
                uIm[q] = fmaf(dxv, Ai[base + c * 16 + r], uIm[q]);
            }
        }
#pragma unroll
        for (int q = 0; q < 4; ++q) {
            aRe[q] = 0.5f * (bRe[q] - uRe[q]);
            aIm[q] = 0.5f * (bIm[q] + uIm[q]);
        }
    }

    // ---- 1-norm -> s -> scale (round-10 verified)
    float colsum = 0.f;
#pragma unroll
    for (int q = 0; q < 4; ++q)
        colsum += sqrtf(aRe[q] * aRe[q] + aIm[q] * aIm[q]);
    colsum += __shfl_xor(colsum, 16);
    colsum += __shfl_xor(colsum, 32);
    float mx = colsum;
    mx = fmaxf(mx, __shfl_xor(mx, 1));
    mx = fmaxf(mx, __shfl_xor(mx, 2));
    mx = fmaxf(mx, __shfl_xor(mx, 4));
    mx = fmaxf(mx, __shfl_xor(mx, 8));

    int s_ = 0;
    if (mx > 1.f) s_ = (int)ceilf(log2f(mx));
    if (s_ < 0) s_ = 0;
    if (s_ > 16) s_ = 16;
    const float sc = exp2f((float)(-s_));
#pragma unroll
    for (int q = 0; q < 4; ++q) { aRe[q] *= sc; aIm[q] *= sc; }

    // ---- helpers -----------------------------------------------------------
    auto pack4 = [&](const float* vR, const float* vI,
                     unsigned* xh, unsigned* xl, unsigned* yh, unsigned* yl) {
#pragma unroll
        for (int p = 0; p < 2; ++p) {
            xh[p] = pk2(vR[2 * p], vR[2 * p + 1]);
            yh[p] = pk2(vI[2 * p], vI[2 * p + 1]);
            xl[p] = pk2(vR[2 * p] - hif(vR[2 * p]), vR[2 * p + 1] - hif(vR[2 * p + 1]));
            yl[p] = pk2(vI[2 * p] - hif(vI[2 * p]), vI[2 * p + 1] - hif(vI[2 * p + 1]));
        }
    };
    auto bset = [&](const unsigned* xh, const unsigned* xl,
                    const unsigned* yh, const unsigned* yl,
                    unsigned* Px, unsigned* PxL, unsigned* Py, unsigned* PyL) {
        Px[0]  = SHF(xh[0], s0); Px[1]  = SHF(xh[1], s0); Px[2]  = SHF(xh[0], s1); Px[3]  = SHF(xh[1], s1);
        PxL[0] = SHF(xl[0], s0); PxL[1] = SHF(xl[1], s0); PxL[2] = SHF(xl[0], s1); PxL[3] = SHF(xl[1], s1);
        Py[0]  = SHF(yh[0], s0); Py[1]  = SHF(yh[1], s0); Py[2]  = SHF(yh[0], s1); Py[3]  = SHF(yh[1], s1);
        PyL[0] = SHF(yl[0], s0); PyL[1] = SHF(yl[1], s0); PyL[2] = SHF(yl[0], s1); PyL[3] = SHF(yl[1], s1);
    };
    // frag[i] = gs ? (Y[i]^sy) : (X[i]^sx)
    auto sel4 = [&](const unsigned* X, const unsigned* Y, unsigned sx, unsigned sy) -> bf16x8 {
        union { unsigned u[4]; bf16x8 v; } r;
#pragma unroll
        for (int i = 0; i < 4; ++i) r.u[i] = gs ? (Y[i] ^ sy) : (X[i] ^ sx);
        return r.v;
    };

    // ---- pack A, set(A)
    unsigned AXh[2], AXl[2], AYh[2], AYl[2];
    pack4(aRe, aIm, AXh, AXl, AYh, AYl);
    unsigned Pxh[4], Pxl[4], Pyh[4], Pyl[4];
    bset(AXh, AXl, AYh, AYl, Pxh, Pxl, Pyh, Pyl);

    // ---- Z = A*A   (A-op presents A1: set planes of A1^T = -conj(A1))
    {
        // computed below into zr/zi
    }
    bf16x8 fh  = sel4(Pxh, Pyh, SG, 0);   // [-X | +Y]
    bf16x8 fl  = sel4(Pxl, Pyl, SG, 0);
    bf16x8 b1h = sel4(Pxh, Pyh, 0, SG);   // B1 = [X ; -Y]
    bf16x8 b1l = sel4(Pxl, Pyl, 0, SG);
    bf16x8 b2h = sel4(Pyh, Pxh, 0, 0);    // B2 = [Y ; X]
    bf16x8 b2l = sel4(Pyl, Pxl, 0, 0);
    f32x4 zr4 = {0.f, 0.f, 0.f, 0.f}, zi4 = {0.f, 0.f, 0.f, 0.f};
    zr4 = MFMA16(fh, b1h, zr4); zr4 = MFMA16(fh, b1l, zr4); zr4 = MFMA16(fl, b1h, zr4);
    zi4 = MFMA16(fh, b2h, zi4); zi4 = MFMA16(fh, b2l, zi4); zi4 = MFMA16(fl, b2h, zi4);

    float zr[4], zi[4];
#pragma unroll
    for (int q = 0; q < 4; ++q) { zr[q] = zr4[q]; zi[q] = zi4[q]; }

    // ---- persistent A-op frags presenting Z (set planes of Z^T = conj(Z))
    unsigned ZXh[2], ZXl[2], ZYh[2], ZYl[2];
    pack4(zr, zi, ZXh, ZXl, ZYh, ZYl);
    {
        unsigned Qxh[4], Qxl[4], Qyh[4], Qyl[4];
        bset(ZXh, ZXl, ZYh, ZYl, Qxh, Qxl, Qyh, Qyl);
        fh = sel4(Qxh, Qyh, 0, SG);       // zf hi: [X | -Y]
        fl = sel4(Qxl, Qyl, 0, SG);       // zf lo
    }
    const bf16x8 zfh = fh, zfl = fl;

    // ---- T = poly(A), S = poly(-A) seeds
    float tR[4], tI[4], sR[4], sI[4];
#pragma unroll
    for (int q = 0; q < 4; ++q) {
        tR[q] = C8 * zr[q] + C7 * aRe[q] + C6 * dq[q];
        tI[q] = C8 * zi[q] + C7 * aIm[q];
        sR[q] = C8 * zr[q] - C7 * aRe[q] + C6 * dq[q];
        sI[q] = C8 * zi[q] - C7 * aIm[q];
    }

    // ---- 3 Horner steps: T <- Z*T + (eI+oA);  S <- Z*S + (eI-oA)
    const float cE[3] = {C4, C2, C0};
    const float cO[3] = {C5, C3, C1};
#pragma unroll
    for (int h = 0; h < 3; ++h) {
        unsigned TXh[2], TXl[2], TYh[2], TYl[2];
        pack4(tR, tI, TXh, TXl, TYh, TYl);
        bset(TXh, TXl, TYh, TYl, Pxh, Pxl, Pyh, Pyl);
        b1h = sel4(Pxh, Pyh, 0, SG); b1l = sel4(Pxl, Pyl, 0, SG);
        b2h = sel4(Pyh, Pxh, 0, 0);  b2l = sel4(Pyl, Pxl, 0, 0);
        f32x4 ar = {cO[h] * aRe[0] + cE[h] * dq[0], cO[h] * aRe[1] + cE[h] * dq[1],
                    cO[h] * aRe[2] + cE[h] * dq[2], cO[h] * aRe[3] + cE[h] * dq[3]};
        f32x4 ai = {cO[h] * aIm[0], cO[h] * aIm[1], cO[h] * aIm[2], cO[h] * aIm[3]};
        ar = MFMA16(zfh, b1h, ar); ar = MFMA16(zfh, b1l, ar); ar = MFMA16(zfl, b1h, ar);
        ai = MFMA16(zfh, b2h, ai); ai = MFMA16(zfh, b2l, ai); ai = MFMA16(zfl, b2h, ai);

        pack4(sR, sI, TXh, TXl, TYh, TYl);
        bset(TXh, TXl, TYh, TYl, Pxh, Pxl, Pyh, Pyl);
        b1h = sel4(Pxh, Pyh, 0, SG); b1l = sel4(Pxl, Pyl, 0, SG);
        b2h = sel4(Pyh, Pxh, 0, 0);  b2l = sel4(Pyl, Pxl, 0, 0);
        f32x4 br = {-cO[h] * aRe[0] + cE[h] * dq[0], -cO[h] * aRe[1] + cE[h] * dq[1],
                    -cO[h] * aRe[2] + cE[h] * dq[2], -cO[h] * aRe[3] + cE[h] * dq[3]};
        f32x4 bi = {-cO[h] * aIm[0], -cO[h] * aIm[1], -cO[h] * aIm[2], -cO[h] * aIm[3]};
        br = MFMA16(zfh, b1h, br); br = MFMA16(zfh, b1l, br); br = MFMA16(zfl, b1h, br);
        bi = MFMA16(zfh, b2h, bi); bi = MFMA16(zfh, b2l, bi); bi = MFMA16(zfl, b2h, bi);

#pragma unroll
        for (int q = 0; q < 4; ++q) {
            tR[q] = ar[q]; tI[q] = ai[q];
            sR[q] = br[q]; sI[q] = bi[q];
        }
    }

    // ---- U = T^T = conj(S)
    float uR[4], uI[4];
#pragma unroll
    for (int q = 0; q < 4; ++q) { uR[q] = sR[q]; uI[q] = -sI[q]; }

    // ---- s squarings via the (T, U=T^T) pair
#pragma unroll 1
    for (int it = 0; it < s_; ++it) {
        unsigned TXh[2], TXl[2], TYh[2], TYl[2];
        unsigned UXh[2], UXl[2], UYh[2], UYl[2];
        pack4(tR, tI, TXh, TXl, TYh, TYl);
        pack4(uR, uI, UXh, UXl, UYh, UYl);
        unsigned Qxh[4], Qxl[4], Qyh[4], Qyl[4];
        bset(TXh, TXl, TYh, TYl, Pxh, Pxl, Pyh, Pyl);   // set(T)
        bset(UXh, UXl, UYh, UYl, Qxh, Qxl, Qyh, Qyl);   // set(U)

        // T_new = T*T : A = plain(set(U)) presents U^T = T; B = B12(set(T))
        const bf16x8 afh = sel4(Qxh, Qyh, 0, 0);
        const bf16x8 afl = sel4(Qxl, Qyl, 0, 0);
        b1h = sel4(Pxh, Pyh, 0, SG); b1l = sel4(Pxl, Pyl, 0, SG);
        f32x4 r = {0.f, 0.f, 0.f, 0.f};
        r = MFMA16(afh, b1h, r); r = MFMA16(afh, b1l, r); r = MFMA16(afl, b1h, r);
        const bool needIm = !(real_only && (it == s_ - 1));
        f32x4 i4 = {0.f, 0.f, 0.f, 0.f};
        if (needIm) {
            b2h = sel4(Pyh, Pxh, 0, 0); b2l = sel4(Pyl, Pxl, 0, 0);
            i4 = MFMA16(afh, b2h, i4); i4 = MFMA16(afh, b2l, i4); i4 = MFMA16(afl, b2h, i4);
        }

        if (it < s_ - 1) {
            // U_new = U*U : A = plain(set(T)) presents T^T = U; B = B12(set(U))
            const bf16x8 a2h = sel4(Pxh, Pyh, 0, 0);
            const bf16x8 a2l = sel4(Pxl, Pyl, 0, 0);
            const bf16x8 c1h = sel4(Qxh, Qyh, 0, SG), c1l = sel4(Qxl, Qyl, 0, SG);
            const bf16x8 c2h = sel4(Qyh, Qxh, 0, 0),  c2l = sel4(Qyl, Qxl, 0, 0);
            f32x4 ur = {0.f, 0.f, 0.f, 0.f}, ui = {0.f, 0.f, 0.f, 0.f};
            ur = MFMA16(a2h, c1h, ur); ur = MFMA16(a2h, c1l, ur); ur = MFMA16(a2l, c1h, ur);
            ui = MFMA16(a2h, c2h, ui); ui = MFMA16(a2h, c2l, ui); ui = MFMA16(a2l, c2h, ui);
#pragma unroll
            for (int q = 0; q < 4; ++q) { uR[q] = ur[q]; uI[q] = ui[q]; }
        }
#pragma unroll
        for (int q = 0; q < 4; ++q) {
            tR[q] = r[q];
            if (needIm) tI[q] = i4[q];
        }
    }

    // ---- write result
    if (real_only) {
        float* po = out + (size_t)m * 256;
#pragma unroll
        for (int q = 0; q < 4; ++q)
            po[(4 * g + q) * 16 + c] = tR[q];
    } else {
        float* po = out + (size_t)m * 512;
#pragma unroll
        for (int q = 0; q < 4; ++q)
            *reinterpret_cast<float2*>(po + ((4 * g + q) * 16 + c) * 2) =
                make_float2(tR[q], tI[q]);
    }
}

// ---------------------------------------------------------------------------
extern "C" void kernel_launch(void* const* d_in, const int* in_sizes, int n_in,
                              void* d_out, int out_size, void* d_ws, size_t ws_size,
                              hipStream_t stream)
{
    const float* dX = (const float*)d_in[0];
    const float* Ar = (const float*)d_in[1];
    const float* Ai = (const float*)d_in[2];
    float* out = (float*)d_out;
    float* ws  = (float*)d_ws;

    const int real_only = (out_size < NMAT * 512) ? 1 : 0;
    const size_t need = (size_t)NMAT * 512 * sizeof(float);
    const int use_ws = (ws_size >= need) ? 1 : 0;

    if (use_ws)
        hipLaunchKernelGGL(ax_kernel, dim3(NN / 8), dim3(256), 0, stream, dX, Ar, Ai, ws);
    hipLaunchKernelGGL(expm_mfma_kernel, dim3(NMAT / 4), dim3(256), 0, stream,
                       dX, Ar, Ai, ws, out, use_ws, real_only);
}

// Round 13
// 319.711 us; speedup vs baseline: 1.0985x; 1.0985x over previous
//
#include <hip/hip_runtime.h>
#include <math.h>

// Problem constants
#define NN       16384
#define IN_DIM   64
#define CC       4
#define NMAT     (NN * CC)

// Taylor coefficients 1/k!
#define C0 1.0f
#define C1 1.0f
#define C2 0.5f
#define C3 0.16666666666666666f
#define C4 0.041666666666666664f
#define C5 0.008333333333333333f
#define C6 0.001388888888888889f
#define C7 1.984126984126984e-4f
#define C8 2.48015873015873e-5f

typedef __attribute__((ext_vector_type(8))) short bf16x8;   // 8 bf16 = 4 VGPR
typedef __attribute__((ext_vector_type(4))) float f32x4;    // C/D frag

#define MFMA16(A, B, C) __builtin_amdgcn_mfma_f32_16x16x32_bf16((A), (B), (C), 0, 0, 0)

// Per-matrix LDS: two colmaj regions (T @0, U @3072), each 4 planes:
//   XH@0, YH@768, XL@1536, YL@2304; column stride 48B (32B data + 16B pad).
#define PXH 0
#define PYH 768
#define LOD 1536              // lo-plane delta (PXL-PXH = PYL-PYH)
#define REG_T 0
#define REG_U 3072
#define MATB  6144
#define WPB   4               // matrices (waves) per 256-thread block

__device__ __forceinline__ float hif(float x) {
    return __builtin_bit_cast(float, __builtin_bit_cast(unsigned, x) & 0xFFFF0000u);
}
__device__ __forceinline__ unsigned pk2(float a, float b) {   // bf16(a)|bf16(b)<<16
    return (__builtin_bit_cast(unsigned, a) >> 16) |
           (__builtin_bit_cast(unsigned, b) & 0xFFFF0000u);
}

// ---------------------------------------------------------------------------
// Phase 1: B[n,c,i,j] = sum_k dX[n,k] * (Ar + i*Ai)[k,c,i,j]  -> ws
// ---------------------------------------------------------------------------
__global__ __launch_bounds__(256)
void ax_kernel(const float* __restrict__ dX, const float* __restrict__ Ar,
               const float* __restrict__ Ai, float* __restrict__ ws)
{
    const int t  = threadIdx.x;
    const int nb = blockIdx.x * 8;
    const int c  = t >> 6;
    const int i  = (t >> 2) & 15;
    const int j0 = (t & 3) * 4;

    float accre[8][4], accim[8][4];
#pragma unroll
    for (int nn_ = 0; nn_ < 8; ++nn_)
#pragma unroll
        for (int jj = 0; jj < 4; ++jj) { accre[nn_][jj] = 0.f; accim[nn_][jj] = 0.f; }

#pragma unroll 2
    for (int k = 0; k < IN_DIM; ++k) {
        const int base = (k * CC + c) * 256 + i * 16 + j0;
        const float4 ar = *reinterpret_cast<const float4*>(Ar + base);
        const float4 ai = *reinterpret_cast<const float4*>(Ai + base);
#pragma unroll
        for (int nn_ = 0; nn_ < 8; ++nn_) {
            const float dxv = dX[(nb + nn_) * IN_DIM + k];
#pragma unroll
            for (int jj = 0; jj < 4; ++jj) {
                accre[nn_][jj] = fmaf(dxv, (&ar.x)[jj], accre[nn_][jj]);
                accim[nn_][jj] = fmaf(dxv, (&ai.x)[jj], accim[nn_][jj]);
            }
        }
    }
#pragma unroll
    for (int nn_ = 0; nn_ < 8; ++nn_) {
        const int m = (nb + nn_) * CC + c;
        float* o = ws + (size_t)m * 512 + (i * 16 + j0) * 2;
        reinterpret_cast<float4*>(o)[0] =
            make_float4(accre[nn_][0], accim[nn_][0], accre[nn_][1], accim[nn_][1]);
        reinterpret_cast<float4*>(o)[1] =
            make_float4(accre[nn_][2], accim[nn_][2], accre[nn_][3], accim[nn_][3]);
    }
}

// ---------------------------------------------------------------------------
// Phase 2 (MFMA, colmaj-only LDS): one matrix per wave.
// Complex 16x16x16 as ONE K=32 mfma group: A=[X|Y], B1=[X;-Y]->Re, B2=[Y;X]->Im.
// f32 precision: bf16 hi/lo split, 3 term-products (round-10 verified).
// ALL A-operands via the transpose-presentation trick (B-style read presents
// M^T): A1^T=-conj(A1) -> [-X|+Y] of colmaj(A1); Z^T=conj(Z) -> [X|-Y];
// generic T via pair-track (T, U=T^T), U seeded as conj(poly(-A)).
// No rowmaj scatter writes, no bpermutes: clean b64 writes + b128 reads only.
// Wave-private regions -> no barriers (same-wave DS ordering).
// ---------------------------------------------------------------------------
__global__ __launch_bounds__(256)
void expm_mfma_kernel(const float* __restrict__ dX, const float* __restrict__ Ar,
                      const float* __restrict__ Ai, const float* __restrict__ ws,
                      float* __restrict__ out, const int use_ws, const int real_only)
{
    __shared__ __align__(16) unsigned char ldsraw[WPB * MATB];

    const int t = threadIdx.x;
    const int w = t >> 6;
    const int l = t & 63;
    unsigned char* L = ldsraw + w * MATB;

    const int m  = blockIdx.x * WPB + w;
    const int n  = m >> 2;
    const int cc = m & 3;

    const int c  = l & 15;         // owned column (C/D); frag col/row
    const int g  = l >> 4;
    const int gh = g & 1;
    const bool gs = (g >= 2);      // k>=16 half -> Y-plane side
    const int colent = c * 48 + gh * 16;
    const int o1 = (gs ? PYH : PXH) + colent;   // B1/plain-hi offset (region-rel)
    const int o2 = (gs ? PXH : PYH) + colent;   // B2-hi offset
    const int wc = c * 48 + g * 8;              // colmaj write offset

    const short ns = (short)0x8000;
    const bf16x8 negall = {ns, ns, ns, ns, ns, ns, ns, ns};
    const bf16x8 zero8  = {0, 0, 0, 0, 0, 0, 0, 0};
    const bf16x8 mB1 = gs ? negall : zero8;   // [X ; -Y] / also conj-presentation
    const bf16x8 mA1 = gs ? zero8 : negall;   // [-X | +Y] (skew-Herm A1 as A-op)

    float dq[4];
#pragma unroll
    for (int q = 0; q < 4; ++q) dq[q] = ((4 * g + q) == c) ? 1.f : 0.f;

    // ---- load AX (C/D ownership) + transposed elements; skew-project
    float aRe[4], aIm[4];
    if (use_ws) {
        const float* gp = ws + (size_t)m * 512;
#pragma unroll
        for (int q = 0; q < 4; ++q) {
            const int r = 4 * g + q;
            const float2 v = *reinterpret_cast<const float2*>(gp + (r * 16 + c) * 2);
            const float2 u = *reinterpret_cast<const float2*>(gp + (c * 16 + r) * 2);
            aRe[q] = 0.5f * (v.x - u.x);
            aIm[q] = 0.5f * (v.y + u.y);
        }
    } else {
        float bRe[4] = {0,0,0,0}, bIm[4] = {0,0,0,0}, uRe[4] = {0,0,0,0}, uIm[4] = {0,0,0,0};
        for (int k = 0; k < IN_DIM; ++k) {
            const float dxv = dX[n * IN_DIM + k];
            const int base = (k * CC + cc) * 256;
#pragma unroll
            for (int q = 0; q < 4; ++q) {
                const int r = 4 * g + q;
                bRe[q] = fmaf(dxv, Ar[base + r * 16 + c], bRe[q]);
                bIm[q] = fmaf(dxv, Ai[base + r * 16 + c], bIm[q]);
                uRe[q] = fmaf(dxv, Ar[base + c * 16 + r], uRe[q]);
                uIm[q] = fmaf(dxv, Ai[base + c * 16 + r], uIm[q]);
            }
        }
#pragma unroll
        for (int q = 0; q < 4; ++q) {
            aRe[q] = 0.5f * (bRe[q] - uRe[q]);
            aIm[q] = 0.5f * (bIm[q] + uIm[q]);
        }
    }

    // ---- 1-norm -> s -> scale (verified)
    float colsum = 0.f;
#pragma unroll
    for (int q = 0; q < 4; ++q)
        colsum += sqrtf(aRe[q] * aRe[q] + aIm[q] * aIm[q]);
    colsum += __shfl_xor(colsum, 16);
    colsum += __shfl_xor(colsum, 32);
    float mx = colsum;
    mx = fmaxf(mx, __shfl_xor(mx, 1));
    mx = fmaxf(mx, __shfl_xor(mx, 2));
    mx = fmaxf(mx, __shfl_xor(mx, 4));
    mx = fmaxf(mx, __shfl_xor(mx, 8));

    int s_ = 0;
    if (mx > 1.f) s_ = (int)ceilf(log2f(mx));
    if (s_ < 0) s_ = 0;
    if (s_ > 16) s_ = 16;
    const float sc = exp2f((float)(-s_));
#pragma unroll
    for (int q = 0; q < 4; ++q) { aRe[q] *= sc; aIm[q] *= sc; }

    // ---- helpers -----------------------------------------------------------
    auto ldx = [&](int off) -> bf16x8 {
        return *reinterpret_cast<const bf16x8*>(L + off);
    };
    // write C/D values to colmaj planes of a region (4x ds_write_b64, clean)
    auto wcol = [&](int region, const float* vR, const float* vI) {
        uint2 xh, yh, xl, yl;
        xh.x = pk2(vR[0], vR[1]); xh.y = pk2(vR[2], vR[3]);
        yh.x = pk2(vI[0], vI[1]); yh.y = pk2(vI[2], vI[3]);
        xl.x = pk2(vR[0] - hif(vR[0]), vR[1] - hif(vR[1]));
        xl.y = pk2(vR[2] - hif(vR[2]), vR[3] - hif(vR[3]));
        yl.x = pk2(vI[0] - hif(vI[0]), vI[1] - hif(vI[1]));
        yl.y = pk2(vI[2] - hif(vI[2]), vI[3] - hif(vI[3]));
        unsigned char* R = L + region + wc;
        *reinterpret_cast<uint2*>(R + PXH)       = xh;
        *reinterpret_cast<uint2*>(R + PYH)       = yh;
        *reinterpret_cast<uint2*>(R + PXH + LOD) = xl;
        *reinterpret_cast<uint2*>(R + PYH + LOD) = yl;
    };
    // plain A-presentation frags of a region's stored matrix W: presents W^T
    auto plainA = [&](int region, bf16x8& h, bf16x8& lo) {
        h  = ldx(region + o1);
        lo = ldx(region + o1 + LOD);
    };
    // acc += (A-op frags) * (matrix stored in region): B1/B2 reads + 3+3 mfma
    auto cmul = [&](const bf16x8 Ah, const bf16x8 Al, int region,
                    f32x4& re, f32x4& im, bool doIm) {
        const bf16x8 b1h = ldx(region + o1) ^ mB1;
        const bf16x8 b1l = ldx(region + o1 + LOD) ^ mB1;
        re = MFMA16(Ah, b1h, re);
        re = MFMA16(Ah, b1l, re);
        re = MFMA16(Al, b1h, re);
        if (doIm) {
            const bf16x8 b2h = ldx(region + o2);
            const bf16x8 b2l = ldx(region + o2 + LOD);
            im = MFMA16(Ah, b2h, im);
            im = MFMA16(Ah, b2l, im);
            im = MFMA16(Al, b2h, im);
        }
    };

    // ---- A1 -> REG_T; Z = A1*A1 (A-op = [-X|+Y] of colmaj(A1))
    wcol(REG_T, aRe, aIm);
    bf16x8 fh = ldx(REG_T + o1) ^ mA1;
    bf16x8 fl = ldx(REG_T + o1 + LOD) ^ mA1;
    f32x4 zr4 = {0.f, 0.f, 0.f, 0.f}, zi4 = {0.f, 0.f, 0.f, 0.f};
    cmul(fh, fl, REG_T, zr4, zi4, true);

    float zr[4], zi[4];
#pragma unroll
    for (int q = 0; q < 4; ++q) { zr[q] = zr4[q]; zi[q] = zi4[q]; }

    // ---- Z -> REG_U; hoist its A-presentation ([X|-Y] = B1-style read)
    wcol(REG_U, zr, zi);
    const bf16x8 zfh = ldx(REG_U + o1) ^ mB1;
    const bf16x8 zfl = ldx(REG_U + o1 + LOD) ^ mB1;

    // ---- seeds: T = C8 Z + C7 A + C6 I;  S = C8 Z - C7 A + C6 I
    float tR[4], tI[4], sR[4], sI[4];
#pragma unroll
    for (int q = 0; q < 4; ++q) {
        tR[q] = C8 * zr[q] + C7 * aRe[q] + C6 * dq[q];
        tI[q] = C8 * zi[q] + C7 * aIm[q];
        sR[q] = C8 * zr[q] - C7 * aRe[q] + C6 * dq[q];
        sI[q] = C8 * zi[q] - C7 * aIm[q];
    }

    // ---- 3 Horner steps: T <- Z*T + (eI+oA);  S <- Z*S + (eI-oA)
    const float cE[3] = {C4, C2, C0};
    const float cO[3] = {C5, C3, C1};
#pragma unroll
    for (int h = 0; h < 3; ++h) {
        wcol(REG_T, tR, tI);
        f32x4 ar = {cO[h] * aRe[0] + cE[h] * dq[0], cO[h] * aRe[1] + cE[h] * dq[1],
                    cO[h] * aRe[2] + cE[h] * dq[2], cO[h] * aRe[3] + cE[h] * dq[3]};
        f32x4 ai = {cO[h] * aIm[0], cO[h] * aIm[1], cO[h] * aIm[2], cO[h] * aIm[3]};
        cmul(zfh, zfl, REG_T, ar, ai, true);

        wcol(REG_U, sR, sI);
        f32x4 br = {-cO[h] * aRe[0] + cE[h] * dq[0], -cO[h] * aRe[1] + cE[h] * dq[1],
                    -cO[h] * aRe[2] + cE[h] * dq[2], -cO[h] * aRe[3] + cE[h] * dq[3]};
        f32x4 bi = {-cO[h] * aIm[0], -cO[h] * aIm[1], -cO[h] * aIm[2], -cO[h] * aIm[3]};
        cmul(zfh, zfl, REG_U, br, bi, true);

#pragma unroll
        for (int q = 0; q < 4; ++q) {
            tR[q] = ar[q]; tI[q] = ai[q];
            sR[q] = br[q]; sI[q] = bi[q];
        }
    }

    // ---- U = T^T = conj(S)
    float uR[4], uI[4];
#pragma unroll
    for (int q = 0; q < 4; ++q) { uR[q] = sR[q]; uI[q] = -sI[q]; }

    // ---- s squarings via the (T, U=T^T) pair; all clean colmaj traffic
#pragma unroll 1
    for (int it = 0; it < s_; ++it) {
        wcol(REG_T, tR, tI);
        wcol(REG_U, uR, uI);

        // T' = T*T : A-op = plain(REG_U) presents U^T = T; B = REG_T
        bf16x8 afh, afl;
        plainA(REG_U, afh, afl);
        const bool needIm = !(real_only && (it == s_ - 1));
        f32x4 r = {0.f, 0.f, 0.f, 0.f}, i4 = {0.f, 0.f, 0.f, 0.f};
        cmul(afh, afl, REG_T, r, i4, needIm);

        if (it < s_ - 1) {
            // U' = U*U : A-op = plain(REG_T) presents T^T = U; B = REG_U
            bf16x8 a2h, a2l;
            plainA(REG_T, a2h, a2l);
            f32x4 ur = {0.f, 0.f, 0.f, 0.f}, ui = {0.f, 0.f, 0.f, 0.f};
            cmul(a2h, a2l, REG_U, ur, ui, true);
#pragma unroll
            for (int q = 0; q < 4; ++q) { uR[q] = ur[q]; uI[q] = ui[q]; }
        }
#pragma unroll
        for (int q = 0; q < 4; ++q) {
            tR[q] = r[q];
            if (needIm) tI[q] = i4[q];
        }
    }

    // ---- write result
    if (real_only) {
        float* po = out + (size_t)m * 256;
#pragma unroll
        for (int q = 0; q < 4; ++q)
            po[(4 * g + q) * 16 + c] = tR[q];
    } else {
        float* po = out + (size_t)m * 512;
#pragma unroll
        for (int q = 0; q < 4; ++q)
            *reinterpret_cast<float2*>(po + ((4 * g + q) * 16 + c) * 2) =
                make_float2(tR[q], tI[q]);
    }
}

// ---------------------------------------------------------------------------
extern "C" void kernel_launch(void* const* d_in, const int* in_sizes, int n_in,
                              void* d_out, int out_size, void* d_ws, size_t ws_size,
                              hipStream_t stream)
{
    const float* dX = (const float*)d_in[0];
    const float* Ar = (const float*)d_in[1];
    const float* Ai = (const float*)d_in[2];
    float* out = (float*)d_out;
    float* ws  = (float*)d_ws;

    const int real_only = (out_size < NMAT * 512) ? 1 : 0;
    const size_t need = (size_t)NMAT * 512 * sizeof(float);
    const int use_ws = (ws_size >= need) ? 1 : 0;

    if (use_ws)
        hipLaunchKernelGGL(ax_kernel, dim3(NN / 8), dim3(256), 0, stream, dX, Ar, Ai, ws);
    hipLaunchKernelGGL(expm_mfma_kernel, dim3(NMAT / WPB), dim3(256), 0, stream,
                       dX, Ar, Ai, ws, out, use_ws, real_only);
}

// Round 14
// 246.700 us; speedup vs baseline: 1.4237x; 1.2960x over previous
//
#include <hip/hip_runtime.h>
#include <math.h>

// Problem constants
#define NN       16384
#define IN_DIM   64
#define CC       4
#define NMAT     (NN * CC)

// Taylor coefficients 1/k!
#define C0 1.0f
#define C1 1.0f
#define C2 0.5f
#define C3 0.16666666666666666f
#define C4 0.041666666666666664f
#define C5 0.008333333333333333f
#define C6 0.001388888888888889f
#define C7 1.984126984126984e-4f
#define C8 2.48015873015873e-5f

typedef __attribute__((ext_vector_type(8))) short bf16x8;   // 8 bf16 = 4 VGPR
typedef __attribute__((ext_vector_type(4))) float f32x4;    // C/D frag

#define MFMA16(A, B, C) __builtin_amdgcn_mfma_f32_16x16x32_bf16((A), (B), (C), 0, 0, 0)

// Two 48B-column-stride regions per matrix, planes staggered by 800B
// (800/16 = 50 ≡ 2 mod 8 -> plane bank-slot decorrelation):
//   region RC @0    : colmaj A, then T          (B-operand + masked A-ops)
//   region RR @3200 : colmaj conj(Z) during Horner; rowmaj(T) in squarings
// Planes within a region: XH@0, YH@800, XL@1600, YL@2400 (LOD=1600).
#define PXH  0
#define PYH  800
#define LOD  1600
#define RC   0
#define RR   3200
#define MATB 6400
#define WPB  4               // matrices (waves) per 256-thread block

__device__ __forceinline__ float hif(float x) {
    return __builtin_bit_cast(float, __builtin_bit_cast(unsigned, x) & 0xFFFF0000u);
}
__device__ __forceinline__ unsigned hi16(float x) {
    return __builtin_bit_cast(unsigned, x) >> 16;
}
__device__ __forceinline__ unsigned pk2(float a, float b) {   // bf16(a)|bf16(b)<<16
    return (__builtin_bit_cast(unsigned, a) >> 16) |
           (__builtin_bit_cast(unsigned, b) & 0xFFFF0000u);
}

// ---------------------------------------------------------------------------
// Phase 1: B[n,c,i,j] = sum_k dX[n,k] * (Ar + i*Ai)[k,c,i,j]  -> ws
// ---------------------------------------------------------------------------
__global__ __launch_bounds__(256)
void ax_kernel(const float* __restrict__ dX, const float* __restrict__ Ar,
               const float* __restrict__ Ai, float* __restrict__ ws)
{
    const int t  = threadIdx.x;
    const int nb = blockIdx.x * 8;
    const int c  = t >> 6;
    const int i  = (t >> 2) & 15;
    const int j0 = (t & 3) * 4;

    float accre[8][4], accim[8][4];
#pragma unroll
    for (int nn_ = 0; nn_ < 8; ++nn_)
#pragma unroll
        for (int jj = 0; jj < 4; ++jj) { accre[nn_][jj] = 0.f; accim[nn_][jj] = 0.f; }

#pragma unroll 2
    for (int k = 0; k < IN_DIM; ++k) {
        const int base = (k * CC + c) * 256 + i * 16 + j0;
        const float4 ar = *reinterpret_cast<const float4*>(Ar + base);
        const float4 ai = *reinterpret_cast<const float4*>(Ai + base);
#pragma unroll
        for (int nn_ = 0; nn_ < 8; ++nn_) {
            const float dxv = dX[(nb + nn_) * IN_DIM + k];
#pragma unroll
            for (int jj = 0; jj < 4; ++jj) {
                accre[nn_][jj] = fmaf(dxv, (&ar.x)[jj], accre[nn_][jj]);
                accim[nn_][jj] = fmaf(dxv, (&ai.x)[jj], accim[nn_][jj]);
            }
        }
    }
#pragma unroll
    for (int nn_ = 0; nn_ < 8; ++nn_) {
        const int m = (nb + nn_) * CC + c;
        float* o = ws + (size_t)m * 512 + (i * 16 + j0) * 2;
        reinterpret_cast<float4*>(o)[0] =
            make_float4(accre[nn_][0], accim[nn_][0], accre[nn_][1], accim[nn_][1]);
        reinterpret_cast<float4*>(o)[1] =
            make_float4(accre[nn_][2], accim[nn_][2], accre[nn_][3], accim[nn_][3]);
    }
}

// ---------------------------------------------------------------------------
// Phase 2 (MFMA): one matrix per wave. r10 structure + r13 mask-presentations
// for A1/Z (no scatter for them) + r9 spectral-norm s.
//   Z0 = A*A (unscaled; A-op = ^mA1 masked colmaj(A))
//   s  = ceil(0.5*log2 ||Z0||_1)   [>= log2 ||A||_2]
//   conj(Z) written colmaj into RR = rowmaj(Z) -> plain A-read presents Z
//   Horner: T <- Z*T + (eI + oA)  (B-op = colmaj(T) in RC)
//   squarings: wcol(T)+wrow-scatter(T); A-op = plain read of rowmaj(T)
// Wave-private regions; same-wave DS ordering -> no barriers.
// ---------------------------------------------------------------------------
__global__ __launch_bounds__(256)
void expm_mfma_kernel(const float* __restrict__ dX, const float* __restrict__ Ar,
                      const float* __restrict__ Ai, const float* __restrict__ ws,
                      float* __restrict__ out, const int use_ws, const int real_only)
{
    __shared__ __align__(16) unsigned char ldsraw[WPB * MATB];

    const int t = threadIdx.x;
    const int w = t >> 6;
    const int l = t & 63;
    unsigned char* L = ldsraw + w * MATB;

    const int m  = blockIdx.x * WPB + w;
    const int n  = m >> 2;
    const int cc = m & 3;

    const int c  = l & 15;         // owned column (C/D); frag row/col
    const int g  = l >> 4;
    const int gh = g & 1;
    const bool gs = (g >= 2);      // k>=16 half -> Y-plane side
    const int colent = c * 48 + gh * 16;
    const int o1 = (gs ? PYH : PXH) + colent;   // B1 / plain-A hi offset
    const int o2 = (gs ? PXH : PYH) + colent;   // B2 hi offset
    const int wc = c * 48 + g * 8;              // colmaj write offset

    const short ns = (short)0x8000;
    const bf16x8 negall = {ns, ns, ns, ns, ns, ns, ns, ns};
    const bf16x8 zero8  = {0, 0, 0, 0, 0, 0, 0, 0};
    const bf16x8 mB1 = gs ? negall : zero8;   // B1 = [X ; -Y]
    const bf16x8 mA1 = gs ? zero8 : negall;   // A-op of skew-Herm A: [-X | +Y]

    float dq[4];
#pragma unroll
    for (int q = 0; q < 4; ++q) dq[q] = ((4 * g + q) == c) ? 1.f : 0.f;

    // ---- load AX (C/D ownership) + transposed elements; skew-project
    float aRe[4], aIm[4];
    if (use_ws) {
        const float* gp = ws + (size_t)m * 512;
#pragma unroll
        for (int q = 0; q < 4; ++q) {
            const int r = 4 * g + q;
            const float2 v = *reinterpret_cast<const float2*>(gp + (r * 16 + c) * 2);
            const float2 u = *reinterpret_cast<const float2*>(gp + (c * 16 + r) * 2);
            aRe[q] = 0.5f * (v.x - u.x);
            aIm[q] = 0.5f * (v.y + u.y);
        }
    } else {
        float bRe[4] = {0,0,0,0}, bIm[4] = {0,0,0,0}, uRe[4] = {0,0,0,0}, uIm[4] = {0,0,0,0};
        for (int k = 0; k < IN_DIM; ++k) {
            const float dxv = dX[n * IN_DIM + k];
            const int base = (k * CC + cc) * 256;
#pragma unroll
            for (int q = 0; q < 4; ++q) {
                const int r = 4 * g + q;
                bRe[q] = fmaf(dxv, Ar[base + r * 16 + c], bRe[q]);
                bIm[q] = fmaf(dxv, Ai[base + r * 16 + c], bIm[q]);
                uRe[q] = fmaf(dxv, Ar[base + c * 16 + r], uRe[q]);
                uIm[q] = fmaf(dxv, Ai[base + c * 16 + r], uIm[q]);
            }
        }
#pragma unroll
        for (int q = 0; q < 4; ++q) {
            aRe[q] = 0.5f * (bRe[q] - uRe[q]);
            aIm[q] = 0.5f * (bIm[q] + uIm[q]);
        }
    }

    // ---- helpers -----------------------------------------------------------
    auto ldx = [&](int off) -> bf16x8 {
        return *reinterpret_cast<const bf16x8*>(L + off);
    };
    // write C/D values to colmaj planes of a region (4x ds_write_b64)
    auto wcol = [&](int region, const float* vR, const float* vI) {
        uint2 xh, yh, xl, yl;
        xh.x = pk2(vR[0], vR[1]); xh.y = pk2(vR[2], vR[3]);
        yh.x = pk2(vI[0], vI[1]); yh.y = pk2(vI[2], vI[3]);
        xl.x = pk2(vR[0] - hif(vR[0]), vR[1] - hif(vR[1]));
        xl.y = pk2(vR[2] - hif(vR[2]), vR[3] - hif(vR[3]));
        yl.x = pk2(vI[0] - hif(vI[0]), vI[1] - hif(vI[1]));
        yl.y = pk2(vI[2] - hif(vI[2]), vI[3] - hif(vI[3]));
        unsigned char* R = L + region + wc;
        *reinterpret_cast<uint2*>(R + PXH)       = xh;
        *reinterpret_cast<uint2*>(R + PYH)       = yh;
        *reinterpret_cast<uint2*>(R + PXH + LOD) = xl;
        *reinterpret_cast<uint2*>(R + PYH + LOD) = yl;
    };
    // scatter-write rowmaj(T) into RR (squarings only)
    auto wrow = [&](const float* vR, const float* vI) {
#pragma unroll
        for (int q = 0; q < 4; ++q) {
            const int rb = RR + (4 * g + q) * 48 + c * 2;
            *reinterpret_cast<unsigned short*>(L + rb + PXH) =
                (unsigned short)hi16(vR[q]);
            *reinterpret_cast<unsigned short*>(L + rb + PYH) =
                (unsigned short)hi16(vI[q]);
            *reinterpret_cast<unsigned short*>(L + rb + PXH + LOD) =
                (unsigned short)hi16(vR[q] - hif(vR[q]));
            *reinterpret_cast<unsigned short*>(L + rb + PYH + LOD) =
                (unsigned short)hi16(vI[q] - hif(vI[q]));
        }
    };
    // acc += (A-frags) * (matrix colmaj in region): B1/B2 reads + 3+3 mfma
    auto cmul = [&](const bf16x8 Ah, const bf16x8 Al, int region,
                    f32x4& re, f32x4& im, bool doIm) {
        const bf16x8 b1h = ldx(region + o1) ^ mB1;
        const bf16x8 b1l = ldx(region + o1 + LOD) ^ mB1;
        re = MFMA16(Ah, b1h, re);
        re = MFMA16(Ah, b1l, re);
        re = MFMA16(Al, b1h, re);
        if (doIm) {
            const bf16x8 b2h = ldx(region + o2);
            const bf16x8 b2l = ldx(region + o2 + LOD);
            im = MFMA16(Ah, b2h, im);
            im = MFMA16(Ah, b2l, im);
            im = MFMA16(Al, b2h, im);
        }
    };

    // ---- unscaled A -> RC; Z0 = A*A  (A-op = masked colmaj(A))
    wcol(RC, aRe, aIm);
    {
        const bf16x8 fh = ldx(RC + o1) ^ mA1;
        const bf16x8 fl = ldx(RC + o1 + LOD) ^ mA1;
        f32x4 zr4 = {0.f, 0.f, 0.f, 0.f}, zi4 = {0.f, 0.f, 0.f, 0.f};
        cmul(fh, fl, RC, zr4, zi4, true);

        // ---- spectral s: ||A||_2^2 = ||Z0||_2 <= ||Z0||_1
        float colsum = 0.f;
#pragma unroll
        for (int q = 0; q < 4; ++q)
            colsum += sqrtf(zr4[q] * zr4[q] + zi4[q] * zi4[q]);
        colsum += __shfl_xor(colsum, 16);
        colsum += __shfl_xor(colsum, 32);
        float mx = colsum;
        mx = fmaxf(mx, __shfl_xor(mx, 1));
        mx = fmaxf(mx, __shfl_xor(mx, 2));
        mx = fmaxf(mx, __shfl_xor(mx, 4));
        mx = fmaxf(mx, __shfl_xor(mx, 8));

        int s_ = 0;
        if (mx > 1.f) s_ = (int)ceilf(0.5f * log2f(mx));
        if (s_ < 0) s_ = 0;
        if (s_ > 16) s_ = 16;
        const float sc1 = exp2f((float)(-s_));
        const float sc2 = sc1 * sc1;

        float zr[4], zi[4], nzi[4];
#pragma unroll
        for (int q = 0; q < 4; ++q) {
            aRe[q] *= sc1; aIm[q] *= sc1;
            zr[q] = zr4[q] * sc2; zi[q] = zi4[q] * sc2;
            nzi[q] = -zi[q];
        }

        // ---- conj(Z) colmaj -> RR  (== rowmaj(Z): plain A-read presents Z)
        wcol(RR, zr, nzi);
        const bf16x8 zfh = ldx(RR + o1);
        const bf16x8 zfl = ldx(RR + o1 + LOD);

        // ---- seeds: T = C8 Z + C7 A + C6 I
        float tR[4], tI[4];
#pragma unroll
        for (int q = 0; q < 4; ++q) {
            tR[q] = C8 * zr[q] + C7 * aRe[q] + C6 * dq[q];
            tI[q] = C8 * zi[q] + C7 * aIm[q];
        }

        // ---- 3 Horner steps: T <- Z*T + (eI + oA)
        const float cE[3] = {C4, C2, C0};
        const float cO[3] = {C5, C3, C1};
#pragma unroll
        for (int h = 0; h < 3; ++h) {
            wcol(RC, tR, tI);
            f32x4 ar = {cO[h] * aRe[0] + cE[h] * dq[0], cO[h] * aRe[1] + cE[h] * dq[1],
                        cO[h] * aRe[2] + cE[h] * dq[2], cO[h] * aRe[3] + cE[h] * dq[3]};
            f32x4 ai = {cO[h] * aIm[0], cO[h] * aIm[1], cO[h] * aIm[2], cO[h] * aIm[3]};
            cmul(zfh, zfl, RC, ar, ai, true);
#pragma unroll
            for (int q = 0; q < 4; ++q) { tR[q] = ar[q]; tI[q] = ai[q]; }
        }

        // ---- s squarings: wcol(T)+wrow(T); A-op = plain rowmaj(T) read
#pragma unroll 1
        for (int it = 0; it < s_; ++it) {
            wcol(RC, tR, tI);
            wrow(tR, tI);
            const bf16x8 afh = ldx(RR + o1);        // rowmaj(T) presents T
            const bf16x8 afl = ldx(RR + o1 + LOD);
            const bool needIm = !(real_only && (it == s_ - 1));
            f32x4 r = {0.f, 0.f, 0.f, 0.f}, i4 = {0.f, 0.f, 0.f, 0.f};
            cmul(afh, afl, RC, r, i4, needIm);
#pragma unroll
            for (int q = 0; q < 4; ++q) {
                tR[q] = r[q];
                if (needIm) tI[q] = i4[q];
            }
        }

        // ---- write result
        if (real_only) {
            float* po = out + (size_t)m * 256;
#pragma unroll
            for (int q = 0; q < 4; ++q)
                po[(4 * g + q) * 16 + c] = tR[q];
        } else {
            float* po = out + (size_t)m * 512;
#pragma unroll
            for (int q = 0; q < 4; ++q)
                *reinterpret_cast<float2*>(po + ((4 * g + q) * 16 + c) * 2) =
                    make_float2(tR[q], tI[q]);
        }
    }
}

// ---------------------------------------------------------------------------
extern "C" void kernel_launch(void* const* d_in, const int* in_sizes, int n_in,
                              void* d_out, int out_size, void* d_ws, size_t ws_size,
                              hipStream_t stream)
{
    const float* dX = (const float*)d_in[0];
    const float* Ar = (const float*)d_in[1];
    const float* Ai = (const float*)d_in[2];
    float* out = (float*)d_out;
    float* ws  = (float*)d_ws;

    const int real_only = (out_size < NMAT * 512) ? 1 : 0;
    const size_t need = (size_t)NMAT * 512 * sizeof(float);
    const int use_ws = (ws_size >= need) ? 1 : 0;

    if (use_ws)
        hipLaunchKernelGGL(ax_kernel, dim3(NN / 8), dim3(256), 0, stream, dX, Ar, Ai, ws);
    hipLaunchKernelGGL(expm_mfma_kernel, dim3(NMAT / WPB), dim3(256), 0, stream,
                       dX, Ar, Ai, ws, out, use_ws, real_only);
}

// Round 17
// 223.896 us; speedup vs baseline: 1.5687x; 1.1018x over previous
//
#include <hip/hip_runtime.h>
#include <math.h>

// Problem constants
#define NN       16384
#define IN_DIM   64
#define CC       4
#define NMAT     (NN * CC)

// Taylor coefficients 1/k!
#define C0 1.0f
#define C1 1.0f
#define C2 0.5f
#define C3 0.16666666666666666f
#define C4 0.041666666666666664f
#define C5 0.008333333333333333f
#define C6 0.001388888888888889f
#define C7 1.984126984126984e-4f
#define C8 2.48015873015873e-5f

typedef __attribute__((ext_vector_type(8))) short bf16x8;   // 8 bf16 = 4 VGPR
typedef __attribute__((ext_vector_type(4))) float f32x4;    // C/D frag

#define MFMA16(A, B, C) __builtin_amdgcn_mfma_f32_16x16x32_bf16((A), (B), (C), 0, 0, 0)

// Two 48B-column-stride regions per matrix, planes at +800B steps:
//   RC @0    : colmaj A, then T (B-operand side of every cmul)
//   RR @3200 : colmaj conj(Z) during Horner; rowmaj(T) in squarings (A-op side)
// Planes: XH@0, YH@800, XL@1600, YL@2400 (LOD=1600).
#define PXH  0
#define PYH  800
#define LOD  1600
#define RC   0
#define RR   3200
#define MATB 6400
#define WPB  4               // matrices (waves) per 256-thread block

__device__ __forceinline__ unsigned fbits(float x) {
    return __builtin_bit_cast(unsigned, x);
}
__device__ __forceinline__ float hif(float x) {
    return __builtin_bit_cast(float, fbits(x) & 0xFFFF0000u);
}
// pack bf16(a) | bf16(b)<<16 as ONE v_perm_b32
__device__ __forceinline__ unsigned pkp(float a, float b) {
    return __builtin_amdgcn_perm(fbits(b), fbits(a), 0x07060302u);
}

// ---------------------------------------------------------------------------
// Phase 1: B[n,c,i,j] = sum_k dX[n,k] * (Ar + i*Ai)[k,c,i,j]  -> ws
// ---------------------------------------------------------------------------
__global__ __launch_bounds__(256)
void ax_kernel(const float* __restrict__ dX, const float* __restrict__ Ar,
               const float* __restrict__ Ai, float* __restrict__ ws)
{
    const int t  = threadIdx.x;
    const int nb = blockIdx.x * 8;
    const int c  = t >> 6;
    const int i  = (t >> 2) & 15;
    const int j0 = (t & 3) * 4;

    float accre[8][4], accim[8][4];
#pragma unroll
    for (int nn_ = 0; nn_ < 8; ++nn_)
#pragma unroll
        for (int jj = 0; jj < 4; ++jj) { accre[nn_][jj] = 0.f; accim[nn_][jj] = 0.f; }

#pragma unroll 2
    for (int k = 0; k < IN_DIM; ++k) {
        const int base = (k * CC + c) * 256 + i * 16 + j0;
        const float4 ar = *reinterpret_cast<const float4*>(Ar + base);
        const float4 ai = *reinterpret_cast<const float4*>(Ai + base);
#pragma unroll
        for (int nn_ = 0; nn_ < 8; ++nn_) {
            const float dxv = dX[(nb + nn_) * IN_DIM + k];
#pragma unroll
            for (int jj = 0; jj < 4; ++jj) {
                accre[nn_][jj] = fmaf(dxv, (&ar.x)[jj], accre[nn_][jj]);
                accim[nn_][jj] = fmaf(dxv, (&ai.x)[jj], accim[nn_][jj]);
            }
        }
    }
#pragma unroll
    for (int nn_ = 0; nn_ < 8; ++nn_) {
        const int m = (nb + nn_) * CC + c;
        float* o = ws + (size_t)m * 512 + (i * 16 + j0) * 2;
        reinterpret_cast<float4*>(o)[0] =
            make_float4(accre[nn_][0], accim[nn_][0], accre[nn_][1], accim[nn_][1]);
        reinterpret_cast<float4*>(o)[1] =
            make_float4(accre[nn_][2], accim[nn_][2], accre[nn_][3], accim[nn_][3]);
    }
}

// ---------------------------------------------------------------------------
// Phase 2 (MFMA): one matrix per wave. Same algorithm as round 14 (passed,
// absmax 0.0039); this round is codegen-only: v_perm packs, precomputed DS
// base pointers with immediate plane offsets, f32x4 state end-to-end.
// ---------------------------------------------------------------------------
__global__ __launch_bounds__(256)
void expm_mfma_kernel(const float* __restrict__ dX, const float* __restrict__ Ar,
                      const float* __restrict__ Ai, const float* __restrict__ ws,
                      float* __restrict__ out, const int use_ws, const int real_only)
{
    __shared__ __align__(16) unsigned char ldsraw[WPB * MATB];

    const int t = threadIdx.x;
    const int w = t >> 6;
    const int l = t & 63;
    unsigned char* const L = ldsraw + w * MATB;

    const int m  = blockIdx.x * WPB + w;
    const int n  = m >> 2;
    const int cc = m & 3;

    const int c  = l & 15;         // owned column (C/D); frag row/col
    const int g  = l >> 4;
    const int gh = g & 1;
    const bool gs = (g >= 2);      // k>=16 half -> Y-plane side
    const int colent = c * 48 + gh * 16;
    const int o1 = (gs ? PYH : PXH) + colent;   // B1 / plain-A hi offset
    const int o2 = (gs ? PXH : PYH) + colent;   // B2 hi offset
    const int wc = c * 48 + g * 8;              // colmaj write offset

    // ---- precomputed DS base pointers (all further offsets are imm consts)
    unsigned char* const pWc  = L + RC + wc;                    // colmaj write, RC
    unsigned char* const pWcR = L + RR + wc;                    // colmaj write, RR
    unsigned char* const pWr0 = L + RR + (4 * g) * 48 + c * 2;  // rowmaj scatter base
    const unsigned char* const pRd1 = L + RC + o1;              // B1-style read (RC)
    const unsigned char* const pRd2 = L + RC + o2;              // B2-style read (RC)
    const unsigned char* const pRdA = L + RR + o1;              // plain A-read (RR)

    const short ns = (short)0x8000;
    const bf16x8 negall = {ns, ns, ns, ns, ns, ns, ns, ns};
    const bf16x8 zero8  = {0, 0, 0, 0, 0, 0, 0, 0};
    const bf16x8 mB1 = gs ? negall : zero8;   // B1 = [X ; -Y]
    const bf16x8 mA1 = gs ? zero8 : negall;   // A-op of skew-Herm A: [-X | +Y]
    const f32x4 fz = {0.f, 0.f, 0.f, 0.f};

    f32x4 dqv;
#pragma unroll
    for (int q = 0; q < 4; ++q) dqv[q] = ((4 * g + q) == c) ? 1.f : 0.f;

    // ---- load AX (C/D ownership) + transposed elements; skew-project
    f32x4 aRv, aIv;
    if (use_ws) {
        const float* gp = ws + (size_t)m * 512;
#pragma unroll
        for (int q = 0; q < 4; ++q) {
            const int r = 4 * g + q;
            const float2 v = *reinterpret_cast<const float2*>(gp + (r * 16 + c) * 2);
            const float2 u = *reinterpret_cast<const float2*>(gp + (c * 16 + r) * 2);
            aRv[q] = 0.5f * (v.x - u.x);
            aIv[q] = 0.5f * (v.y + u.y);
        }
    } else {
        float bRe[4] = {0,0,0,0}, bIm[4] = {0,0,0,0}, uRe[4] = {0,0,0,0}, uIm[4] = {0,0,0,0};
        for (int k = 0; k < IN_DIM; ++k) {
            const float dxv = dX[n * IN_DIM + k];
            const int base = (k * CC + cc) * 256;
#pragma unroll
            for (int q = 0; q < 4; ++q) {
                const int r = 4 * g + q;
                bRe[q] = fmaf(dxv, Ar[base + r * 16 + c], bRe[q]);
                bIm[q] = fmaf(dxv, Ai[base + r * 16 + c], bIm[q]);
                uRe[q] = fmaf(dxv, Ar[base + c * 16 + r], uRe[q]);
                uIm[q] = fmaf(dxv, Ai[base + c * 16 + r], uIm[q]);
            }
        }
#pragma unroll
        for (int q = 0; q < 4; ++q) {
            aRv[q] = 0.5f * (bRe[q] - uRe[q]);
            aIv[q] = 0.5f * (bIm[q] + uIm[q]);
        }
    }

    // ---- helpers (all DS via fixed pointers + imm offsets) -------------------
    auto wcolV = [&](unsigned char* Rb, const f32x4 vR, const f32x4 vI) {
        uint2 xh, yh, xl, yl;
        xh.x = pkp(vR[0], vR[1]); xh.y = pkp(vR[2], vR[3]);
        yh.x = pkp(vI[0], vI[1]); yh.y = pkp(vI[2], vI[3]);
        const float r0 = vR[0] - hif(vR[0]), r1 = vR[1] - hif(vR[1]);
        const float r2 = vR[2] - hif(vR[2]), r3 = vR[3] - hif(vR[3]);
        const float i0 = vI[0] - hif(vI[0]), i1 = vI[1] - hif(vI[1]);
        const float i2 = vI[2] - hif(vI[2]), i3 = vI[3] - hif(vI[3]);
        xl.x = pkp(r0, r1); xl.y = pkp(r2, r3);
        yl.x = pkp(i0, i1); yl.y = pkp(i2, i3);
        *reinterpret_cast<uint2*>(Rb + PXH)       = xh;
        *reinterpret_cast<uint2*>(Rb + PYH)       = yh;
        *reinterpret_cast<uint2*>(Rb + PXH + LOD) = xl;
        *reinterpret_cast<uint2*>(Rb + PYH + LOD) = yl;
    };
    auto wrowV = [&](const f32x4 vR, const f32x4 vI) {
#pragma unroll
        for (int q = 0; q < 4; ++q) {
            unsigned char* p = pWr0 + q * 48;
            *reinterpret_cast<unsigned short*>(p + PXH) =
                (unsigned short)(fbits(vR[q]) >> 16);
            *reinterpret_cast<unsigned short*>(p + PYH) =
                (unsigned short)(fbits(vI[q]) >> 16);
            const float lr = vR[q] - hif(vR[q]);
            const float li = vI[q] - hif(vI[q]);
            *reinterpret_cast<unsigned short*>(p + PXH + LOD) =
                (unsigned short)(fbits(lr) >> 16);
            *reinterpret_cast<unsigned short*>(p + PYH + LOD) =
                (unsigned short)(fbits(li) >> 16);
        }
    };
    // acc += (A-frags) * (matrix colmaj in RC): B1/B2 imm-offset reads + 3+3 mfma
    auto cmulV = [&](const bf16x8 Ah, const bf16x8 Al,
                     f32x4& re, f32x4& im, bool doIm) {
        const bf16x8 b1h = *reinterpret_cast<const bf16x8*>(pRd1) ^ mB1;
        const bf16x8 b1l = *reinterpret_cast<const bf16x8*>(pRd1 + LOD) ^ mB1;
        re = MFMA16(Ah, b1h, re);
        re = MFMA16(Ah, b1l, re);
        re = MFMA16(Al, b1h, re);
        if (doIm) {
            const bf16x8 b2h = *reinterpret_cast<const bf16x8*>(pRd2);
            const bf16x8 b2l = *reinterpret_cast<const bf16x8*>(pRd2 + LOD);
            im = MFMA16(Ah, b2h, im);
            im = MFMA16(Ah, b2l, im);
            im = MFMA16(Al, b2h, im);
        }
    };

    // ---- unscaled A -> RC colmaj; Z0 = A*A (A-op = masked read of colmaj(A))
    wcolV(pWc, aRv, aIv);
    {
        const bf16x8 fh = *reinterpret_cast<const bf16x8*>(pRd1) ^ mA1;
        const bf16x8 fl = *reinterpret_cast<const bf16x8*>(pRd1 + LOD) ^ mA1;
        f32x4 zr4 = fz, zi4 = fz;
        cmulV(fh, fl, zr4, zi4, true);

        // ---- spectral s: ||A||_2^2 = ||Z0||_2 <= ||Z0||_1
        float colsum = 0.f;
#pragma unroll
        for (int q = 0; q < 4; ++q)
            colsum += sqrtf(zr4[q] * zr4[q] + zi4[q] * zi4[q]);
        colsum += __shfl_xor(colsum, 16);
        colsum += __shfl_xor(colsum, 32);
        float mx = colsum;
        mx = fmaxf(mx, __shfl_xor(mx, 1));
        mx = fmaxf(mx, __shfl_xor(mx, 2));
        mx = fmaxf(mx, __shfl_xor(mx, 4));
        mx = fmaxf(mx, __shfl_xor(mx, 8));

        int s_ = 0;
        if (mx > 1.f) s_ = (int)ceilf(0.5f * log2f(mx));
        if (s_ < 0) s_ = 0;
        if (s_ > 16) s_ = 16;
        const float sc1 = exp2f((float)(-s_));
        const float sc2 = sc1 * sc1;

        f32x4 zrv, ziv, nzv;
#pragma unroll
        for (int q = 0; q < 4; ++q) {
            aRv[q] *= sc1; aIv[q] *= sc1;
            zrv[q] = zr4[q] * sc2; ziv[q] = zi4[q] * sc2;
            nzv[q] = -ziv[q];
        }

        // ---- conj(Z) colmaj -> RR (== rowmaj(Z)); plain A-read presents Z
        wcolV(pWcR, zrv, nzv);
        const bf16x8 zfh = *reinterpret_cast<const bf16x8*>(pRdA);
        const bf16x8 zfl = *reinterpret_cast<const bf16x8*>(pRdA + LOD);

        // ---- seeds: T = C8 Z + C7 A + C6 I
        f32x4 tRv, tIv;
#pragma unroll
        for (int q = 0; q < 4; ++q) {
            tRv[q] = C8 * zrv[q] + C7 * aRv[q] + C6 * dqv[q];
            tIv[q] = C8 * ziv[q] + C7 * aIv[q];
        }

        // ---- 3 Horner steps: T <- Z*T + (eI + oA)
        const float cE[3] = {C4, C2, C0};
        const float cO[3] = {C5, C3, C1};
#pragma unroll
        for (int h = 0; h < 3; ++h) {
            wcolV(pWc, tRv, tIv);
            f32x4 ar, ai;
#pragma unroll
            for (int q = 0; q < 4; ++q) {
                ar[q] = cO[h] * aRv[q] + cE[h] * dqv[q];
                ai[q] = cO[h] * aIv[q];
            }
            cmulV(zfh, zfl, ar, ai, true);
            tRv = ar; tIv = ai;
        }

        // ---- s squarings: wcol(T)+wrow(T); A-op = plain rowmaj(T) read
#pragma unroll 1
        for (int it = 0; it < s_; ++it) {
            wcolV(pWc, tRv, tIv);
            wrowV(tRv, tIv);
            const bf16x8 afh = *reinterpret_cast<const bf16x8*>(pRdA);
            const bf16x8 afl = *reinterpret_cast<const bf16x8*>(pRdA + LOD);
            const bool needIm = !(real_only && (it == s_ - 1));
            f32x4 r = fz, i4 = fz;
            cmulV(afh, afl, r, i4, needIm);
            tRv = r;
            if (needIm) tIv = i4;
        }

        // ---- write result
        if (real_only) {
            float* po = out + (size_t)m * 256;
#pragma unroll
            for (int q = 0; q < 4; ++q)
                po[(4 * g + q) * 16 + c] = tRv[q];
        } else {
            float* po = out + (size_t)m * 512;
#pragma unroll
            for (int q = 0; q < 4; ++q)
                *reinterpret_cast<float2*>(po + ((4 * g + q) * 16 + c) * 2) =
                    make_float2(tRv[q], tIv[q]);
        }
    }
}

// ---------------------------------------------------------------------------
extern "C" void kernel_launch(void* const* d_in, const int* in_sizes, int n_in,
                              void* d_out, int out_size, void* d_ws, size_t ws_size,
                              hipStream_t stream)
{
    const float* dX = (const float*)d_in[0];
    const float* Ar = (const float*)d_in[1];
    const float* Ai = (const float*)d_in[2];
    float* out = (float*)d_out;
    float* ws  = (float*)d_ws;

    const int real_only = (out_size < NMAT * 512) ? 1 : 0;
    const size_t need = (size_t)NMAT * 512 * sizeof(float);
    const int use_ws = (ws_size >= need) ? 1 : 0;

    if (use_ws)
        hipLaunchKernelGGL(ax_kernel, dim3(NN / 8), dim3(256), 0, stream, dX, Ar, Ai, ws);
    hipLaunchKernelGGL(expm_mfma_kernel, dim3(NMAT / WPB), dim3(256), 0, stream,
                       dX, Ar, Ai, ws, out, use_ws, real_only);
}